// Round 7
// baseline (126.088 us; speedup 1.0000x reference)
//
#include <hip/hip_runtime.h>

#define DEV __device__ __forceinline__

typedef __attribute__((ext_vector_type(8))) short bf16x8;
typedef __attribute__((ext_vector_type(4))) short bf16x4;
typedef __attribute__((ext_vector_type(4))) float f32x4;
typedef __attribute__((ext_vector_type(4))) unsigned int u32x4;

constexpr int Bb = 8;
constexpr int Nn = 1024;
constexpr int DIMm = 512;
constexpr int Hh = 8;
constexpr int Dh = 64;
constexpr int Mm = Bb * Nn;  // 8192
constexpr float LN10K = 9.210340371976184f;   // ln(10000)
constexpr float LOG2E = 1.4426950408889634f;  // log2(e)

DEV short f2bf(float f) {
  unsigned int u = __float_as_uint(f);
  u += 0x7fffu + ((u >> 16) & 1u);  // RNE
  return (short)(u >> 16);
}

DEV unsigned int cvtpk(float lo, float hi) {  // dword = {bf16(lo), bf16(hi)}
  unsigned int r;
  asm("v_cvt_pk_bf16_f32 %0, %1, %2" : "=v"(r) : "v"(lo), "v"(hi));
  return r;
}

DEV bf16x8 comb(bf16x4 lo, bf16x4 hi) {
  bf16x8 r;
  r[0] = lo[0]; r[1] = lo[1]; r[2] = lo[2]; r[3] = lo[3];
  r[4] = hi[0]; r[5] = hi[1]; r[6] = hi[2]; r[7] = hi[3];
  return r;
}

DEV f32x4 mfma16(bf16x8 a, bf16x8 b, f32x4 c) {
  return __builtin_amdgcn_mfma_f32_16x16x32_bf16(a, b, c, 0, 0, 0);
}

DEV void gload16(const void* g, void* l) {
  __builtin_amdgcn_global_load_lds(
      (const __attribute__((address_space(1))) void*)g,
      (__attribute__((address_space(3))) void*)l, 16, 0, 0);
}

// ---------------------------------------------------------------------------
// prep: x -> bf16 ; w_qkv -> transposed bf16 [1536][512] ; w_out -> [512][512];
// RoPE cos/sin table [N][32] float2
// ---------------------------------------------------------------------------
__global__ void prep_kernel(const float* __restrict__ x, const float* __restrict__ wq,
                            const float* __restrict__ wo, short* __restrict__ x_bf,
                            short* __restrict__ wqkvT, short* __restrict__ woutT,
                            float2* __restrict__ tab) {
  int stride = gridDim.x * blockDim.x;
  int t = blockIdx.x * blockDim.x + threadIdx.x;
  for (int i = t; i < Mm * DIMm / 4; i += stride) {
    float4 v = ((const float4*)x)[i];
    bf16x4 o;
    o[0] = f2bf(v.x); o[1] = f2bf(v.y); o[2] = f2bf(v.z); o[3] = f2bf(v.w);
    *(bf16x4*)(x_bf + (size_t)i * 4) = o;
  }
  for (int i = t; i < 1536 * 512; i += stride) {
    int n = i >> 9, k = i & 511;
    wqkvT[i] = f2bf(wq[(size_t)k * 1536 + n]);
  }
  for (int i = t; i < 512 * 512; i += stride) {
    int n = i >> 9, k = i & 511;
    woutT[i] = f2bf(wo[(size_t)k * 512 + n]);
  }
  for (int i = t; i < Nn * 32; i += stride) {
    int n = i >> 5, d2 = i & 31;
    float fr = (float)n * __expf(-(float)(2 * d2) * (LN10K / 64.f));
    float sn, cs;
    __sincosf(fr, &sn, &cs);
    tab[i] = make_float2(cs, sn);
  }
}

// ---------------------------------------------------------------------------
// GEMM: A[Mx512] bf16 row-major, Bt[Ncols x 512] bf16 (pre-transposed).
// QKV==1: epilogue applies RoPE (table) + q-scale(0.125) and writes Q/K/V in
//   MFMA-fragment-order global layout (65536 shorts per bh):
//   Q,K (A/B-operand frag, row=n, k=d):
//     off = (n>>4)*1024 + (d>>5)*512 + ((n&15) + 16*((d&15)>>2))*8
//           + ((d&3) | ((d&16)>>2))
//   V (B-operand frag of PV, row=d, k=j):
//     off = (j>>6)*4096 + ((d>>4)*2 + ((j>>5)&1))*512
//           + ((d&15) + 16*((j&15)>>2))*8 + ((j&3) | ((j&16)>>2))
// QKV==0: plain f32 store.
// ---------------------------------------------------------------------------
template <int QKV>
__global__ __launch_bounds__(256) void gemm_k(const short* __restrict__ A,
                                              const short* __restrict__ Bt,
                                              float* __restrict__ outF,
                                              short* __restrict__ qr,
                                              short* __restrict__ kr,
                                              short* __restrict__ vt,
                                              const float2* __restrict__ tab) {
  __shared__ short Al[128][40];
  __shared__ short Bl[128][40];
  const int tid = threadIdx.x;
  const int lane = tid & 63;
  const int wid = tid >> 6;
  const int wm = wid >> 1, wn = wid & 1;
  const int li = lane & 15, g4 = (lane >> 4) << 2;
  const int m0 = blockIdx.x * 128, n0 = blockIdx.y * 128;

  f32x4 zero4 = {0.f, 0.f, 0.f, 0.f};
  f32x4 acc[4][4];
#pragma unroll
  for (int i = 0; i < 4; ++i)
#pragma unroll
    for (int j = 0; j < 4; ++j) acc[i][j] = zero4;

  for (int kt = 0; kt < 512; kt += 32) {
#pragma unroll
    for (int p = 0; p < 2; ++p) {
      int e = (tid + p * 256) * 8;
      int r = e >> 5, c = e & 31;
      *(u32x4*)(&Al[r][c]) = *(const u32x4*)(A + (size_t)(m0 + r) * 512 + kt + c);
      *(u32x4*)(&Bl[r][c]) = *(const u32x4*)(Bt + (size_t)(n0 + r) * 512 + kt + c);
    }
    __syncthreads();
    bf16x8 af[4], bfr[4];
#pragma unroll
    for (int mt = 0; mt < 4; ++mt) {
      int row = wm * 64 + mt * 16 + li;
      af[mt] = comb(*(const bf16x4*)(&Al[row][g4]), *(const bf16x4*)(&Al[row][16 + g4]));
    }
#pragma unroll
    for (int nt = 0; nt < 4; ++nt) {
      int row = wn * 64 + nt * 16 + li;
      bfr[nt] = comb(*(const bf16x4*)(&Bl[row][g4]), *(const bf16x4*)(&Bl[row][16 + g4]));
    }
#pragma unroll
    for (int mt = 0; mt < 4; ++mt)
#pragma unroll
      for (int nt = 0; nt < 4; ++nt)
        acc[mt][nt] = mfma16(af[mt], bfr[nt], acc[mt][nt]);
    __syncthreads();
  }

  if (QKV == 0) {
#pragma unroll
    for (int mt = 0; mt < 4; ++mt) {
      int mb = m0 + wm * 64 + mt * 16 + g4;
#pragma unroll
      for (int nt = 0; nt < 4; ++nt) {
        int c = n0 + wn * 64 + nt * 16 + li;
#pragma unroll
        for (int r = 0; r < 4; ++r) outF[(size_t)(mb + r) * 512 + c] = acc[mt][nt][r];
      }
    }
  } else {
    const int sec = n0 >> 9;  // 0=q 1=k 2=v
#pragma unroll
    for (int mt = 0; mt < 4; ++mt) {
      int mb = m0 + wm * 64 + mt * 16 + g4;
      int b_ = mb >> 10;
      int nb = mb & 1023;  // token index; nb ≡ g4 (mod 16)
#pragma unroll
      for (int nt = 0; nt < 4; ++nt) {
        int c = n0 + wn * 64 + nt * 16 + li;
        int cs = c & 511;
        int hh = cs >> 6, d = cs & 63;
        size_t bhoff = (size_t)(b_ * Hh + hh) * 65536;
        if (sec == 2) {
          int dt = d >> 4, liD = d & 15;
          int kkJ = (nb >> 5) & 1;
          int gj = (nb & 15) >> 2;
          int s0 = (nb & 16) >> 2;  // 0 or 4
          size_t off = bhoff + (size_t)(nb >> 6) * 4096 +
                       (size_t)((dt * 2 + kkJ) * 512) + (size_t)(liD + 16 * gj) * 8 + s0;
          uint2 st;
          st.x = cvtpk(acc[mt][nt][0], acc[mt][nt][1]);
          st.y = cvtpk(acc[mt][nt][2], acc[mt][nt][3]);
          *(uint2*)(vt + off) = st;
        } else {
          int kkD = d >> 5;
          int gd = (d & 15) >> 2;
          int sD = (d & 3) | ((d & 16) >> 2);
          size_t off = bhoff + (size_t)(nb >> 4) * 1024 + (size_t)(kkD * 512) +
                       (size_t)((nb & 15) + 16 * gd) * 8 + sD;
          short* dst = (sec == 0 ? qr : kr) + off;
#pragma unroll
          for (int r = 0; r < 4; ++r) {
            float v0 = acc[mt][nt][r];
            float vp = __shfl_xor(v0, 1, 64);  // RoPE pair partner (adjacent d)
            float2 cssn = tab[(size_t)(nb + r) * 32 + (d >> 1)];
            float rot = (d & 1) ? vp : -vp;
            float res = v0 * cssn.x + rot * cssn.y;
            if (sec == 0) res *= 0.125f;  // Dh^-0.5 (e-domain; LOG2E applied in exp)
            dst[(size_t)r * 8] = f2bf(res);
          }
        }
      }
    }
  }
}

// ---------------------------------------------------------------------------
// Flash attention v7: 8-wave macro-block (512 thr), Q-tile 256 rows/block
// (32 rows/wave = two 16-row frags mt=0,1), grid = 64 bh x 4 it = 256 blocks
// = 1 block/CU. 2-phase double-buffered LDS pipeline (KVBLK=64) as v6; K/V
// ds_reads and V-frags shared across both row-frags -> 16 ds_read + 32 MFMA
// per wave per tile. K/V staged traffic /4 vs v6.
// ---------------------------------------------------------------------------
constexpr int KVB = 64;
constexpr int NTT = Nn / KVB;  // 16

__global__ __launch_bounds__(512, 2) void attn_k(const short* __restrict__ qf_g,
                                                 const short* __restrict__ kf_g,
                                                 const short* __restrict__ vf_g,
                                                 const float* __restrict__ bias,
                                                 short* __restrict__ ao) {
  __shared__ short Kls[2][4096];  // [buf][64j x 64d frag-order], 8 KB each
  __shared__ short Vls[2][4096];  // [buf][64d x 64j frag-order], 8 KB each
  const int tid = threadIdx.x, lane = tid & 63, w = tid >> 6;  // w in 0..7
  const int li = lane & 15, g4 = (lane >> 4) << 2;
  // Block mapping: h pin to XCD, it fast, b_ slow.
  const int bid = blockIdx.x;
  const int h = bid & 7;
  const int it = (bid >> 3) & 3;
  const int b_ = bid >> 5;
  const int bh = b_ * 8 + h;
  const int i0 = it * 256;               // block q-row base
  const int iw = i0 + w * 32;            // wave q-row base (32 rows)

  // Q fragments: mt=0,1 row-frags, kk=0,1 k-halves
  const short* qb = qf_g + (size_t)bh * 65536 + (size_t)(it * 16 + w * 2) * 1024 +
                    (size_t)lane * 8;
  bf16x8 qf[2][2];
#pragma unroll
  for (int mt = 0; mt < 2; ++mt)
#pragma unroll
    for (int kk = 0; kk < 2; ++kk)
      qf[mt][kk] = *(const bf16x8*)(qb + mt * 1024 + kk * 512);

  const short* kb = kf_g + (size_t)bh * 65536;
  const short* vb = vf_g + (size_t)bh * 65536;
  // bias row pointers for the two row-frags (rows iw+li, iw+16+li)
  const float* br0 = bias + ((size_t)h * Nn + iw + li) * Nn + g4;
  const float* br1 = br0 + (size_t)16 * Nn;

  float m_run[2] = {-1e30f, -1e30f};
  float l_run[2] = {0.f, 0.f};
  f32x4 zero4 = {0.f, 0.f, 0.f, 0.f};
  f32x4 acc[4][2];  // [dt][mt]
#pragma unroll
  for (int i = 0; i < 4; ++i) {
    acc[i][0] = zero4;
    acc[i][1] = zero4;
  }

  // ---- staging: 1 gload16 per thread for K, 1 for V (8 KB each) ----
#define STAGE_TILE(T, BUF)                                              \
  do {                                                                  \
    gload16(kb + (size_t)(T) * 4096 + (size_t)tid * 8,                  \
            &Kls[BUF][(size_t)(w * 64) * 8]);                           \
    gload16(vb + (size_t)(T) * 4096 + (size_t)tid * 8,                  \
            &Vls[BUF][(size_t)(w * 64) * 8]);                           \
  } while (0)

  f32x4 bbA[4][2], bbB[4][2];

  // prologue
  STAGE_TILE(0, 0);
#pragma unroll
  for (int js = 0; js < 4; ++js) {
    bbA[js][0] = *(const f32x4*)(br0 + js * 16);
    bbA[js][1] = *(const f32x4*)(br1 + js * 16);
  }
  asm volatile("s_waitcnt vmcnt(0)" ::: "memory");
  __builtin_amdgcn_s_barrier();

  int cur = 0;
#pragma unroll 1
  for (int t = 0; t < NTT; ++t) {
    // phase 1: issue next tile's staging + bias prefetch
    if (t + 1 < NTT) {
      STAGE_TILE(t + 1, cur ^ 1);
#pragma unroll
      for (int js = 0; js < 4; ++js) {
        bbB[js][0] = *(const f32x4*)(br0 + (t + 1) * 64 + js * 16);
        bbB[js][1] = *(const f32x4*)(br1 + (t + 1) * 64 + js * 16);
      }
    }

    // phase 2: compute current tile from LDS
    const short* KB = &Kls[cur][0];
    const short* VB = &Vls[cur][0];
    f32x4 s[4][2];
    __builtin_amdgcn_s_setprio(1);
#pragma unroll
    for (int js = 0; js < 4; ++js) {
      bf16x8 k0 = *(const bf16x8*)(KB + js * 1024 + lane * 8);
      bf16x8 k1 = *(const bf16x8*)(KB + js * 1024 + 512 + lane * 8);
#pragma unroll
      for (int mt = 0; mt < 2; ++mt) {
        f32x4 sa = mfma16(k0, qf[mt][0], bbA[js][mt]);
        s[js][mt] = mfma16(k1, qf[mt][1], sa);
      }
    }
    __builtin_amdgcn_s_setprio(0);

    // row max per row-frag
    float mx[2];
#pragma unroll
    for (int mt = 0; mt < 2; ++mt) {
      float a = fmaxf(fmaxf(fmaxf(s[0][mt][0], s[0][mt][1]), fmaxf(s[0][mt][2], s[0][mt][3])),
                      fmaxf(fmaxf(s[1][mt][0], s[1][mt][1]), fmaxf(s[1][mt][2], s[1][mt][3])));
      float b = fmaxf(fmaxf(fmaxf(s[2][mt][0], s[2][mt][1]), fmaxf(s[2][mt][2], s[2][mt][3])),
                      fmaxf(fmaxf(s[3][mt][0], s[3][mt][1]), fmaxf(s[3][mt][2], s[3][mt][3])));
      float m = fmaxf(a, b);
      m = fmaxf(m, __shfl_xor(m, 16, 64));
      m = fmaxf(m, __shfl_xor(m, 32, 64));
      mx[mt] = m;
    }

    // defer-max (joint over both row-frags to stay wave-uniform)
    bool ok = (mx[0] - m_run[0] <= 8.0f) && (mx[1] - m_run[1] <= 8.0f);
    if (!__all(ok)) {
#pragma unroll
      for (int mt = 0; mt < 2; ++mt) {
        float mn = fmaxf(m_run[mt], mx[mt]);
        float sc = __builtin_amdgcn_exp2f((m_run[mt] - mn) * LOG2E);
        l_run[mt] *= sc;
        m_run[mt] = mn;
        float fs0 = __shfl(sc, g4 + 0, 64), fs1 = __shfl(sc, g4 + 1, 64);
        float fs2 = __shfl(sc, g4 + 2, 64), fs3 = __shfl(sc, g4 + 3, 64);
#pragma unroll
        for (int dt = 0; dt < 4; ++dt) {
          acc[dt][mt][0] *= fs0; acc[dt][mt][1] *= fs1;
          acc[dt][mt][2] *= fs2; acc[dt][mt][3] *= fs3;
        }
      }
    }

    // exp + row-sum + pack
    bf16x8 pf[2][2];  // [kk][mt]
#pragma unroll
    for (int mt = 0; mt < 2; ++mt) {
      float nm = -m_run[mt] * LOG2E;
      float rs = 0.f;
#pragma unroll
      for (int js = 0; js < 4; ++js)
#pragma unroll
        for (int r = 0; r < 4; ++r) {
          float p = __builtin_amdgcn_exp2f(__builtin_fmaf(s[js][mt][r], LOG2E, nm));
          s[js][mt][r] = p;
          rs += p;
        }
      rs += __shfl_xor(rs, 16, 64);
      rs += __shfl_xor(rs, 32, 64);
      l_run[mt] += rs;
#pragma unroll
      for (int kk = 0; kk < 2; ++kk) {
        union { bf16x8 v8; unsigned int d[4]; } u;
        u.d[0] = cvtpk(s[2 * kk][mt][0], s[2 * kk][mt][1]);
        u.d[1] = cvtpk(s[2 * kk][mt][2], s[2 * kk][mt][3]);
        u.d[2] = cvtpk(s[2 * kk + 1][mt][0], s[2 * kk + 1][mt][1]);
        u.d[3] = cvtpk(s[2 * kk + 1][mt][2], s[2 * kk + 1][mt][3]);
        pf[kk][mt] = u.v8;
      }
    }

    // PV: V-frags shared across row-frags
    __builtin_amdgcn_s_setprio(1);
#pragma unroll
    for (int dt = 0; dt < 4; ++dt) {
      bf16x8 vf0 = *(const bf16x8*)(VB + (dt * 2 + 0) * 512 + lane * 8);
      bf16x8 vf1 = *(const bf16x8*)(VB + (dt * 2 + 1) * 512 + lane * 8);
#pragma unroll
      for (int mt = 0; mt < 2; ++mt) {
        f32x4 a = mfma16(pf[0][mt], vf0, acc[dt][mt]);
        acc[dt][mt] = mfma16(pf[1][mt], vf1, a);
      }
    }
    __builtin_amdgcn_s_setprio(0);

    // phase 3: sync buffers
    asm volatile("s_waitcnt vmcnt(0)" ::: "memory");
    __builtin_amdgcn_s_barrier();
#pragma unroll
    for (int js = 0; js < 4; ++js) {
      bbA[js][0] = bbB[js][0];
      bbA[js][1] = bbB[js][1];
    }
    cur ^= 1;
  }
#undef STAGE_TILE

#pragma unroll
  for (int mt = 0; mt < 2; ++mt) {
    float rl = 1.f / l_run[mt];
    float fr0 = __shfl(rl, g4 + 0, 64), fr1 = __shfl(rl, g4 + 1, 64);
    float fr2 = __shfl(rl, g4 + 2, 64), fr3 = __shfl(rl, g4 + 3, 64);
#pragma unroll
    for (int dt = 0; dt < 4; ++dt) {
      float fr[4] = {fr0, fr1, fr2, fr3};
#pragma unroll
      for (int r = 0; r < 4; ++r) {
        int i_ = iw + mt * 16 + g4 + r;
        ao[((size_t)(b_ * Nn + i_)) * 512 + h * 64 + dt * 16 + li] =
            f2bf(acc[dt][mt][r] * fr[r]);
      }
    }
  }
}

// ---------------------------------------------------------------------------
extern "C" void kernel_launch(void* const* d_in, const int* in_sizes, int n_in,
                              void* d_out, int out_size, void* d_ws, size_t ws_size,
                              hipStream_t stream) {
  const float* x = (const float*)d_in[0];
  const float* pb = (const float*)d_in[1];
  const float* wq = (const float*)d_in[2];
  const float* wo = (const float*)d_in[3];
  float* out = (float*)d_out;

  short* w = (short*)d_ws;
  short* x_bf = w;  w += (size_t)Mm * DIMm;      // 8 MB
  short* wqkvT = w; w += 1536 * 512;             // 1.5 MB
  short* woutT = w; w += 512 * 512;              // 0.5 MB
  short* qr = w;    w += (size_t)Mm * DIMm;      // 8 MB (frag-order)
  short* kr = w;    w += (size_t)Mm * DIMm;      // 8 MB (frag-order)
  short* vt = w;    w += (size_t)Mm * DIMm;      // 8 MB (frag-order)
  float2* tab = (float2*)w; w += Nn * 32 * 4;    // 256 KB
  short* ao = x_bf;  // x_bf dead after qkv GEMM

  prep_kernel<<<1024, 256, 0, stream>>>(x, wq, wo, x_bf, wqkvT, woutT, tab);
  gemm_k<1><<<dim3(64, 12), 256, 0, stream>>>(x_bf, wqkvT, nullptr, qr, kr, vt, tab);
  attn_k<<<256, 512, 0, stream>>>(qr, kr, vt, pb, ao);
  gemm_k<0><<<dim3(64, 4), 256, 0, stream>>>(ao, woutT, out, nullptr, nullptr, nullptr, tab);
}